// Round 1
// baseline (847.599 us; speedup 1.0000x reference)
//
#include <hip/hip_runtime.h>
#include <math.h>

#define NFEAT 128
#define NHID 128
#define NCLASS 40

// ---------------- CSR build ----------------
__global__ void k_hist(const int* __restrict__ dst, int E, int* __restrict__ cnt) {
  int i = blockIdx.x * blockDim.x + threadIdx.x;
  int stride = gridDim.x * blockDim.x;
  for (; i < E; i += stride) atomicAdd(&cnt[dst[i]], 1);
}

// block of 256 threads scans 1024 elements
__global__ void k_scan1(const int* __restrict__ cnt, int* __restrict__ off,
                        int* __restrict__ bsum, int n) {
  __shared__ int tmp[256];
  int tid = threadIdx.x;
  int base = blockIdx.x * 1024 + tid * 4;
  int v0 = 0, v1 = 0, v2 = 0, v3 = 0;
  if (base + 0 < n) v0 = cnt[base + 0];
  if (base + 1 < n) v1 = cnt[base + 1];
  if (base + 2 < n) v2 = cnt[base + 2];
  if (base + 3 < n) v3 = cnt[base + 3];
  int s = v0 + v1 + v2 + v3;
  tmp[tid] = s;
  __syncthreads();
  for (int d = 1; d < 256; d <<= 1) {
    int t = (tid >= d) ? tmp[tid - d] : 0;
    __syncthreads();
    tmp[tid] += t;
    __syncthreads();
  }
  int excl = tmp[tid] - s;
  if (base + 0 < n) off[base + 0] = excl;
  excl += v0;
  if (base + 1 < n) off[base + 1] = excl;
  excl += v1;
  if (base + 2 < n) off[base + 2] = excl;
  excl += v2;
  if (base + 3 < n) off[base + 3] = excl;
  if (tid == 255) bsum[blockIdx.x] = tmp[255];
}

// single block of 128 threads scans <=128 block sums
__global__ void k_scan2(const int* __restrict__ bsum, int* __restrict__ boff, int nb) {
  __shared__ int tmp[128];
  int tid = threadIdx.x;
  int v = (tid < nb) ? bsum[tid] : 0;
  tmp[tid] = v;
  __syncthreads();
  for (int d = 1; d < 128; d <<= 1) {
    int t = (tid >= d) ? tmp[tid - d] : 0;
    __syncthreads();
    tmp[tid] += t;
    __syncthreads();
  }
  boff[tid] = tmp[tid] - v;  // exclusive
}

__global__ void k_scan3(int* __restrict__ off, const int* __restrict__ boff,
                        int* __restrict__ cursor, int n, int E) {
  int i = blockIdx.x * blockDim.x + threadIdx.x;
  if (i < n) {
    int o = off[i] + boff[i >> 10];
    off[i] = o;
    cursor[i] = o;
  }
  if (i == 0) off[n] = E;
}

__global__ void k_fill(const int* __restrict__ src, const int* __restrict__ dst, int E,
                       int* __restrict__ cursor, int* __restrict__ col) {
  int i = blockIdx.x * blockDim.x + threadIdx.x;
  int stride = gridDim.x * blockDim.x;
  for (; i < E; i += stride) {
    int d = dst[i];
    int p = atomicAdd(&cursor[d], 1);
    col[p] = src[i];
  }
}

// ---------------- weight concat/pad ----------------
// Wcat1/Wcat2: [128][256] = [Wl | Wr]; Wcat3: [128][128] = [W3l pad to 64 | W3r pad to 64]
__global__ void k_prep(const float* __restrict__ W1l, const float* __restrict__ W1r,
                       const float* __restrict__ W2l, const float* __restrict__ W2r,
                       const float* __restrict__ W3l, const float* __restrict__ W3r,
                       float* __restrict__ Wc1, float* __restrict__ Wc2,
                       float* __restrict__ Wc3) {
  int idx = blockIdx.x * blockDim.x + threadIdx.x;
  if (idx < 128 * 256) {
    int r = idx >> 8, c = idx & 255;
    Wc1[idx] = (c < 128) ? W1l[r * 128 + c] : W1r[r * 128 + (c - 128)];
    Wc2[idx] = (c < 128) ? W2l[r * 128 + c] : W2r[r * 128 + (c - 128)];
  } else {
    int j = idx - 128 * 256;
    if (j < 128 * 128) {
      int r = j >> 7, c = j & 127;
      float v = 0.f;
      if (c < 64) {
        if (c < NCLASS) v = W3l[r * NCLASS + c];
      } else {
        int c2 = c - 64;
        if (c2 < NCLASS) v = W3r[r * NCLASS + c2];
      }
      Wc3[j] = v;
    }
  }
}

// ---------------- fused dual GEMM ----------------
// A [n][128] row-major, Wcat [128][ncb*64]; first ncb/2 col-blocks -> outY, rest -> outR.
// Output stride = (ncb/2)*64. Block: 64 rows, 4x4 per-thread register tile.
#define AST 132  // padded LDS stride for A tile

#define MAD4(ACC, AX, WV)            \
  ACC.x = fmaf(AX, WV.x, ACC.x);     \
  ACC.y = fmaf(AX, WV.y, ACC.y);     \
  ACC.z = fmaf(AX, WV.z, ACC.z);     \
  ACC.w = fmaf(AX, WV.w, ACC.w);

__global__ __launch_bounds__(256) void k_gemm(const float* __restrict__ A,
                                              const float* __restrict__ Wcat, int n,
                                              int ncb, float* __restrict__ outY,
                                              float* __restrict__ outR) {
  __shared__ float aS[64 * AST];
  __shared__ float wS[128 * 64];
  int tid = threadIdx.x;
  int rowBase = blockIdx.x * 64;

  // stage 64 rows of A (zero-fill OOB rows)
  for (int idx = tid; idx < 64 * 32; idx += 256) {
    int r = idx >> 5, k4 = idx & 31;
    int g = rowBase + r;
    float4 v = make_float4(0.f, 0.f, 0.f, 0.f);
    if (g < n) v = ((const float4*)A)[(size_t)g * 32 + k4];
    *(float4*)&aS[r * AST + k4 * 4] = v;
  }

  int wstride = ncb * 64;
  int ncbY = ncb >> 1;
  int DOUTP = ncbY * 64;
  int tr = tid >> 4, tc = tid & 15;
  int r0 = tr * 4, c0 = tc * 4;

  for (int cb = 0; cb < ncb; ++cb) {
    __syncthreads();  // protect wS (and first time: aS staging done)
    for (int idx = tid; idx < 128 * 16; idx += 256) {
      int kr = idx >> 4, c4 = idx & 15;
      *(float4*)&wS[kr * 64 + c4 * 4] =
          *(const float4*)&Wcat[kr * wstride + cb * 64 + c4 * 4];
    }
    __syncthreads();

    float4 acc0 = {0.f, 0.f, 0.f, 0.f}, acc1 = acc0, acc2 = acc0, acc3 = acc0;
#pragma unroll 4
    for (int k = 0; k < 128; k += 4) {
      float4 a0 = *(float4*)&aS[(r0 + 0) * AST + k];
      float4 a1 = *(float4*)&aS[(r0 + 1) * AST + k];
      float4 a2 = *(float4*)&aS[(r0 + 2) * AST + k];
      float4 a3 = *(float4*)&aS[(r0 + 3) * AST + k];
      float4 w0 = *(float4*)&wS[(k + 0) * 64 + c0];
      float4 w1 = *(float4*)&wS[(k + 1) * 64 + c0];
      float4 w2 = *(float4*)&wS[(k + 2) * 64 + c0];
      float4 w3 = *(float4*)&wS[(k + 3) * 64 + c0];
      MAD4(acc0, a0.x, w0); MAD4(acc0, a0.y, w1); MAD4(acc0, a0.z, w2); MAD4(acc0, a0.w, w3);
      MAD4(acc1, a1.x, w0); MAD4(acc1, a1.y, w1); MAD4(acc1, a1.z, w2); MAD4(acc1, a1.w, w3);
      MAD4(acc2, a2.x, w0); MAD4(acc2, a2.y, w1); MAD4(acc2, a2.z, w2); MAD4(acc2, a2.w, w3);
      MAD4(acc3, a3.x, w0); MAD4(acc3, a3.y, w1); MAD4(acc3, a3.z, w2); MAD4(acc3, a3.w, w3);
    }

    float* outP;
    int colBase;
    if (cb < ncbY) {
      outP = outY;
      colBase = cb * 64;
    } else {
      outP = outR;
      colBase = (cb - ncbY) * 64;
    }
    int g0 = rowBase + r0;
    if (g0 + 0 < n) *(float4*)&outP[(size_t)(g0 + 0) * DOUTP + colBase + c0] = acc0;
    if (g0 + 1 < n) *(float4*)&outP[(size_t)(g0 + 1) * DOUTP + colBase + c0] = acc1;
    if (g0 + 2 < n) *(float4*)&outP[(size_t)(g0 + 2) * DOUTP + colBase + c0] = acc2;
    if (g0 + 3 < n) *(float4*)&outP[(size_t)(g0 + 3) * DOUTP + colBase + c0] = acc3;
  }
}

// ---------------- aggregation (d=128): one wave per node ----------------
template <bool RELU>
__global__ void k_agg128(const float* __restrict__ Y, const float* __restrict__ R,
                         const float* __restrict__ bias, const int* __restrict__ off,
                         const int* __restrict__ col, int n, float* __restrict__ out) {
  int wid = (blockIdx.x * blockDim.x + threadIdx.x) >> 6;
  int lane = threadIdx.x & 63;
  if (wid >= n) return;
  int s = off[wid], e = off[wid + 1];
  const float2* Y2 = (const float2*)Y;
  float ax = 0.f, ay = 0.f;
  int j = s;
  for (; j + 2 <= e; j += 2) {
    int s0 = col[j], s1 = col[j + 1];
    float2 v0 = Y2[(size_t)s0 * 64 + lane];
    float2 v1 = Y2[(size_t)s1 * 64 + lane];
    ax += v0.x + v1.x;
    ay += v0.y + v1.y;
  }
  if (j < e) {
    int s0 = col[j];
    float2 v0 = Y2[(size_t)s0 * 64 + lane];
    ax += v0.x;
    ay += v0.y;
  }
  float inv = 1.0f / fmaxf((float)(e - s), 1.0f);
  float2 r = ((const float2*)R)[(size_t)wid * 64 + lane];
  float2 b = ((const float2*)bias)[lane];
  float ox = ax * inv + b.x + r.x;
  float oy = ay * inv + b.y + r.y;
  if (RELU) {
    ox = fmaxf(ox, 0.f);
    oy = fmaxf(oy, 0.f);
  }
  ((float2*)out)[(size_t)wid * 64 + lane] = make_float2(ox, oy);
}

// ---------------- layer-3 aggregation + log_softmax ----------------
// Y,R strided 64 (cols 40..63 are zero padding). out: [n][40] log_softmax.
__global__ void k_agg3(const float* __restrict__ Y, const float* __restrict__ R,
                       const float* __restrict__ b3, const int* __restrict__ off,
                       const int* __restrict__ col, int n, float* __restrict__ out) {
  int wid = (blockIdx.x * blockDim.x + threadIdx.x) >> 6;
  int lane = threadIdx.x & 63;
  if (wid >= n) return;
  int s = off[wid], e = off[wid + 1];
  float acc = 0.f;
  int j = s;
  for (; j + 2 <= e; j += 2) {
    int s0 = col[j], s1 = col[j + 1];
    acc += Y[(size_t)s0 * 64 + lane] + Y[(size_t)s1 * 64 + lane];
  }
  if (j < e) acc += Y[(size_t)col[j] * 64 + lane];
  float inv = 1.0f / fmaxf((float)(e - s), 1.0f);
  float val = -INFINITY;
  if (lane < NCLASS)
    val = acc * inv + b3[lane] + R[(size_t)wid * 64 + lane];
  float m = val;
  for (int o = 32; o > 0; o >>= 1) m = fmaxf(m, __shfl_xor(m, o));
  float ex = (lane < NCLASS) ? expf(val - m) : 0.f;
  float sum = ex;
  for (int o = 32; o > 0; o >>= 1) sum += __shfl_xor(sum, o);
  float ls = logf(sum);
  if (lane < NCLASS) out[(size_t)wid * NCLASS + lane] = val - m - ls;
}

extern "C" void kernel_launch(void* const* d_in, const int* in_sizes, int n_in,
                              void* d_out, int out_size, void* d_ws, size_t ws_size,
                              hipStream_t stream) {
  const float* x = (const float*)d_in[0];
  const int* ei = (const int*)d_in[1];
  const float* W1l = (const float*)d_in[2];
  const float* b1 = (const float*)d_in[3];
  const float* W1r = (const float*)d_in[4];
  const float* W2l = (const float*)d_in[5];
  const float* b2 = (const float*)d_in[6];
  const float* W2r = (const float*)d_in[7];
  const float* W3l = (const float*)d_in[8];
  const float* b3 = (const float*)d_in[9];
  const float* W3r = (const float*)d_in[10];

  int N = in_sizes[0] / NFEAT;
  int E = in_sizes[1] / 2;
  const int* src = ei;
  const int* dst = ei + E;

  char* w = (char*)d_ws;
  auto alloc = [&](size_t bytes) {
    void* p = (void*)w;
    w += (bytes + 255) & ~(size_t)255;
    return p;
  };
  int* off = (int*)alloc((size_t)(N + 1) * 4);
  int* cursor = (int*)alloc((size_t)N * 4);
  int* col = (int*)alloc((size_t)E * 4);
  int* bsum = (int*)alloc(256 * 4);
  int* boff = (int*)alloc(256 * 4);
  float* Wc1 = (float*)alloc(128 * 256 * 4);
  float* Wc2 = (float*)alloc(128 * 256 * 4);
  float* Wc3 = (float*)alloc(128 * 128 * 4);
  float* bufY = (float*)alloc((size_t)N * 128 * 4);
  float* bufA = (float*)alloc((size_t)N * 128 * 4);

  float* outLS = (float*)d_out;                    // [N][40]
  float* emb = (float*)d_out + (size_t)N * NCLASS; // [N][128]

  // CSR build (cursor doubles as the histogram buffer)
  hipMemsetAsync(cursor, 0, (size_t)N * 4, stream);
  k_hist<<<2048, 256, 0, stream>>>(dst, E, cursor);
  int nb = (N + 1023) / 1024;
  k_scan1<<<nb, 256, 0, stream>>>(cursor, off, bsum, N);
  k_scan2<<<1, 128, 0, stream>>>(bsum, boff, nb);
  k_scan3<<<(N + 255) / 256, 256, 0, stream>>>(off, boff, cursor, N, E);
  k_fill<<<2048, 256, 0, stream>>>(src, dst, E, cursor, col);

  k_prep<<<(128 * 256 + 128 * 128 + 255) / 256, 256, 0, stream>>>(
      W1l, W1r, W2l, W2r, W3l, W3r, Wc1, Wc2, Wc3);

  int gb = (N + 63) / 64;
  int ab = (N * 64 + 255) / 256;

  // layer 1: y1 = x@W1l -> bufY ; r1 = x@W1r -> bufA ; h1 = relu(agg+b1+r1) -> bufA
  k_gemm<<<gb, 256, 0, stream>>>(x, Wc1, N, 4, bufY, bufA);
  k_agg128<true><<<ab, 256, 0, stream>>>(bufY, bufA, b1, off, col, N, bufA);

  // layer 2: h2 -> emb slice of d_out
  k_gemm<<<gb, 256, 0, stream>>>(bufA, Wc2, N, 4, bufY, bufA);
  k_agg128<true><<<ab, 256, 0, stream>>>(bufY, bufA, b2, off, col, N, emb);

  // layer 3 (width 40 padded to 64) + fused log_softmax
  k_gemm<<<gb, 256, 0, stream>>>(emb, Wc3, N, 2, bufY, bufA);
  k_agg3<<<ab, 256, 0, stream>>>(bufY, bufA, b3, off, col, N, outLS);
}

// Round 2
// 568.442 us; speedup vs baseline: 1.4911x; 1.4911x over previous
//
#include <hip/hip_runtime.h>
#include <math.h>

#define NCLASS 40

typedef float f32x4 __attribute__((ext_vector_type(4)));
typedef __bf16 bf16x8 __attribute__((ext_vector_type(8)));

typedef __attribute__((address_space(1))) const void gv_t;
typedef __attribute__((address_space(3))) void lv_t;
#define GLOAD_LDS16(g, l) __builtin_amdgcn_global_load_lds((gv_t*)(g), (lv_t*)(l), 16, 0, 0)

__device__ inline unsigned short f2bf(float f) {
  unsigned u = __float_as_uint(f);
  unsigned r = (u + 0x7fff + ((u >> 16) & 1)) >> 16;
  return (unsigned short)r;
}
__device__ inline float bflo(unsigned v) { return __uint_as_float(v << 16); }
__device__ inline float bfhi(unsigned v) { return __uint_as_float(v & 0xffff0000u); }

// ---------------- CSR build ----------------
__global__ void k_hist(const int* __restrict__ dst, int E, int* __restrict__ cnt) {
  int i = blockIdx.x * blockDim.x + threadIdx.x;
  int stride = gridDim.x * blockDim.x;
  for (; i < E; i += stride) atomicAdd(&cnt[dst[i]], 1);
}

__global__ void k_scan1(const int* __restrict__ cnt, int* __restrict__ off,
                        int* __restrict__ bsum, int n) {
  __shared__ int tmp[256];
  int tid = threadIdx.x;
  int base = blockIdx.x * 1024 + tid * 4;
  int v0 = 0, v1 = 0, v2 = 0, v3 = 0;
  if (base + 0 < n) v0 = cnt[base + 0];
  if (base + 1 < n) v1 = cnt[base + 1];
  if (base + 2 < n) v2 = cnt[base + 2];
  if (base + 3 < n) v3 = cnt[base + 3];
  int s = v0 + v1 + v2 + v3;
  tmp[tid] = s;
  __syncthreads();
  for (int d = 1; d < 256; d <<= 1) {
    int t = (tid >= d) ? tmp[tid - d] : 0;
    __syncthreads();
    tmp[tid] += t;
    __syncthreads();
  }
  int excl = tmp[tid] - s;
  if (base + 0 < n) off[base + 0] = excl;
  excl += v0;
  if (base + 1 < n) off[base + 1] = excl;
  excl += v1;
  if (base + 2 < n) off[base + 2] = excl;
  excl += v2;
  if (base + 3 < n) off[base + 3] = excl;
  if (tid == 255) bsum[blockIdx.x] = tmp[255];
}

__global__ void k_scan2(const int* __restrict__ bsum, int* __restrict__ boff, int nb) {
  __shared__ int tmp[128];
  int tid = threadIdx.x;
  int v = (tid < nb) ? bsum[tid] : 0;
  tmp[tid] = v;
  __syncthreads();
  for (int d = 1; d < 128; d <<= 1) {
    int t = (tid >= d) ? tmp[tid - d] : 0;
    __syncthreads();
    tmp[tid] += t;
    __syncthreads();
  }
  boff[tid] = tmp[tid] - v;
}

__global__ void k_scan3(int* __restrict__ off, const int* __restrict__ boff,
                        int* __restrict__ cursor, int n, int E) {
  int i = blockIdx.x * blockDim.x + threadIdx.x;
  if (i < n) {
    int o = off[i] + boff[i >> 10];
    off[i] = o;
    cursor[i] = o;
  }
  if (i == 0) off[n] = E;
}

__global__ void k_fill(const int* __restrict__ src, const int* __restrict__ dst, int E,
                       int* __restrict__ cursor, int* __restrict__ col) {
  int i = blockIdx.x * blockDim.x + threadIdx.x;
  int stride = gridDim.x * blockDim.x;
  for (; i < E; i += stride) {
    int d = dst[i];
    int p = atomicAdd(&cursor[d], 1);
    col[p] = src[i];
  }
}

// ---------------- casts / weight prep ----------------
__global__ void k_cast(const float4* __restrict__ x, uint4* __restrict__ xb, int n8) {
  int i = blockIdx.x * blockDim.x + threadIdx.x;
  if (i >= n8) return;
  float4 a = x[i * 2], b = x[i * 2 + 1];
  uint4 o;
  o.x = (unsigned)f2bf(a.x) | ((unsigned)f2bf(a.y) << 16);
  o.y = (unsigned)f2bf(a.z) | ((unsigned)f2bf(a.w) << 16);
  o.z = (unsigned)f2bf(b.x) | ((unsigned)f2bf(b.y) << 16);
  o.w = (unsigned)f2bf(b.z) | ((unsigned)f2bf(b.w) << 16);
  xb[i] = o;
}

// Wth layout: [half][COLS][128] bf16, row-of-128-k contiguous. half0=Wl^T, half1=Wr^T.
__global__ void k_prepw(const float* __restrict__ W1l, const float* __restrict__ W1r,
                        const float* __restrict__ W2l, const float* __restrict__ W2r,
                        const float* __restrict__ W3l, const float* __restrict__ W3r,
                        unsigned short* __restrict__ Wth1, unsigned short* __restrict__ Wth2,
                        unsigned short* __restrict__ Wth3) {
  int idx = blockIdx.x * blockDim.x + threadIdx.x;
  if (idx < 32768) {
    int h = idx >> 14, c = (idx >> 7) & 127, k = idx & 127;
    const float* W = h ? W1r : W1l;
    Wth1[idx] = f2bf(W[k * 128 + c]);
  } else if (idx < 65536) {
    int j = idx - 32768;
    int h = j >> 14, c = (j >> 7) & 127, k = j & 127;
    const float* W = h ? W2r : W2l;
    Wth2[j] = f2bf(W[k * 128 + c]);
  } else if (idx < 65536 + 16384) {
    int j = idx - 65536;
    int h = j >> 13, c = (j >> 7) & 63, k = j & 127;
    float v = 0.f;
    if (c < NCLASS) v = (h ? W3r : W3l)[k * NCLASS + c];
    Wth3[j] = f2bf(v);
  }
}

// ---------------- mean aggregation over bf16 rows (d=128) ----------------
__global__ void k_aggb(const unsigned* __restrict__ X, const int* __restrict__ off,
                       const int* __restrict__ col, int n, unsigned* __restrict__ out) {
  int wid = (blockIdx.x * blockDim.x + threadIdx.x) >> 6;
  int lane = threadIdx.x & 63;
  if (wid >= n) return;
  int s = off[wid], e = off[wid + 1];
  float ax = 0.f, ay = 0.f;
  int j = s;
  for (; j + 2 <= e; j += 2) {
    int s0 = col[j], s1 = col[j + 1];
    unsigned v0 = X[(size_t)s0 * 64 + lane];
    unsigned v1 = X[(size_t)s1 * 64 + lane];
    ax += bflo(v0) + bflo(v1);
    ay += bfhi(v0) + bfhi(v1);
  }
  if (j < e) {
    unsigned v0 = X[(size_t)col[j] * 64 + lane];
    ax += bflo(v0);
    ay += bfhi(v0);
  }
  float inv = 1.0f / fmaxf((float)(e - s), 1.0f);
  out[(size_t)wid * 64 + lane] =
      (unsigned)f2bf(ax * inv) | ((unsigned)f2bf(ay * inv) << 16);
}

// ---------------- MFMA GEMM: [mean|root] (K=256) @ Wth -> epilogue ----------------
// EPI 0: relu -> outB bf16 [n][128]
// EPI 1: relu -> outB bf16 [n][128] AND outF f32 [n][128]
// EPI 2: +b3, log_softmax over 40 cols -> outF f32 [n][40]  (COLS=64)
template <int COLS, int EPI>
__global__ __launch_bounds__(256) void k_gemm_mfma(
    const unsigned short* __restrict__ Aagg, const unsigned short* __restrict__ Aroot,
    const unsigned short* __restrict__ Wth, const float* __restrict__ bias, int n,
    float* __restrict__ outF, unsigned short* __restrict__ outB) {
  constexpr int RF = (COLS == 128) ? 4 : 2;
  constexpr int CF = 4;
  __shared__ unsigned short aS[128 * 128];
  __shared__ unsigned short wS[COLS * 128];
  int tid = threadIdx.x;
  int w = tid >> 6, lane = tid & 63, l15 = lane & 15, kg = lane >> 4;
  int rowBase = blockIdx.x * 128;
  int r0, c0;
  if (COLS == 128) {
    r0 = (w >> 1) * 64;
    c0 = (w & 1) * 64;
  } else {
    r0 = w * 32;
    c0 = 0;
  }

  f32x4 acc[RF][CF];
#pragma unroll
  for (int i = 0; i < RF; ++i)
#pragma unroll
    for (int j = 0; j < CF; ++j) acc[i][j] = (f32x4){0.f, 0.f, 0.f, 0.f};

#pragma unroll
  for (int half = 0; half < 2; ++half) {
    if (half) __syncthreads();  // all waves done reading LDS of half 0
    // stage A half (128 rows x 256B), swizzled source -> linear LDS
    {
      const unsigned short* As = half ? Aroot : Aagg;
#pragma unroll
      for (int it = 0; it < 8; ++it) {
        int row = it * 16 + (tid >> 4);
        int g = rowBase + row;
        g = (g < n) ? g : (n - 1);
        int cb = (tid & 15) << 4;
        int sb = cb ^ ((row & 7) << 4);
        const char* src = (const char*)(As + (size_t)g * 128) + sb;
        char* dst = (char*)aS + it * 4096 + (tid >> 6) * 1024;
        GLOAD_LDS16(src, dst);
      }
      const unsigned short* Ws = Wth + (size_t)half * COLS * 128;
#pragma unroll
      for (int it = 0; it < COLS / 16; ++it) {
        int c = it * 16 + (tid >> 4);
        int cb = (tid & 15) << 4;
        int sb = cb ^ ((c & 7) << 4);
        const char* src = (const char*)(Ws + (size_t)c * 128) + sb;
        char* dst = (char*)wS + it * 4096 + (tid >> 6) * 1024;
        GLOAD_LDS16(src, dst);
      }
      asm volatile("s_waitcnt vmcnt(0)" ::: "memory");
      __syncthreads();
    }
    // compute half: 4 k-steps of 32
#pragma unroll
    for (int ks = 0; ks < 4; ++ks) {
      int kb = ks * 64 + kg * 16;
      bf16x8 av[RF], bv[CF];
#pragma unroll
      for (int i = 0; i < RF; ++i) {
        int row = r0 + i * 16 + l15;
        av[i] = *(const bf16x8*)((const char*)aS + row * 256 + (kb ^ ((row & 7) << 4)));
      }
#pragma unroll
      for (int j = 0; j < CF; ++j) {
        int c = c0 + j * 16 + l15;
        bv[j] = *(const bf16x8*)((const char*)wS + c * 256 + (kb ^ ((c & 7) << 4)));
      }
#pragma unroll
      for (int i = 0; i < RF; ++i)
#pragma unroll
        for (int j = 0; j < CF; ++j)
          acc[i][j] = __builtin_amdgcn_mfma_f32_16x16x32_bf16(av[i], bv[j], acc[i][j], 0, 0, 0);
    }
  }

  // epilogue
  if (EPI == 2) {
    float b0 = bias[l15];
    float b1 = bias[16 + l15];
    float b2 = (32 + l15 < NCLASS) ? bias[32 + l15] : 0.f;
    bool val2 = l15 < 8;
#pragma unroll
    for (int i = 0; i < RF; ++i) {
#pragma unroll
      for (int r = 0; r < 4; ++r) {
        int row = rowBase + r0 + i * 16 + kg * 4 + r;
        float v0 = acc[i][0][r] + b0;
        float v1 = acc[i][1][r] + b1;
        float v2 = val2 ? acc[i][2][r] + b2 : -INFINITY;
        float m = fmaxf(fmaxf(v0, v1), v2);
        m = fmaxf(m, __shfl_xor(m, 8));
        m = fmaxf(m, __shfl_xor(m, 4));
        m = fmaxf(m, __shfl_xor(m, 2));
        m = fmaxf(m, __shfl_xor(m, 1));
        float s = expf(v0 - m) + expf(v1 - m) + (val2 ? expf(v2 - m) : 0.f);
        s += __shfl_xor(s, 8);
        s += __shfl_xor(s, 4);
        s += __shfl_xor(s, 2);
        s += __shfl_xor(s, 1);
        float ls = logf(s);
        if (row < n) {
          outF[(size_t)row * NCLASS + l15] = v0 - m - ls;
          outF[(size_t)row * NCLASS + 16 + l15] = v1 - m - ls;
          if (val2) outF[(size_t)row * NCLASS + 32 + l15] = v2 - m - ls;
        }
      }
    }
  } else {
    float bcol[CF];
#pragma unroll
    for (int j = 0; j < CF; ++j) bcol[j] = bias[c0 + j * 16 + l15];
#pragma unroll
    for (int i = 0; i < RF; ++i) {
#pragma unroll
      for (int r = 0; r < 4; ++r) {
        int row = rowBase + r0 + i * 16 + kg * 4 + r;
        if (row >= n) continue;
#pragma unroll
        for (int j = 0; j < CF; ++j) {
          float v = fmaxf(acc[i][j][r] + bcol[j], 0.f);
          int c = c0 + j * 16 + l15;
          outB[(size_t)row * 128 + c] = f2bf(v);
          if (EPI == 1) outF[(size_t)row * 128 + c] = v;
        }
      }
    }
  }
}

extern "C" void kernel_launch(void* const* d_in, const int* in_sizes, int n_in,
                              void* d_out, int out_size, void* d_ws, size_t ws_size,
                              hipStream_t stream) {
  const float* x = (const float*)d_in[0];
  const int* ei = (const int*)d_in[1];
  const float* W1l = (const float*)d_in[2];
  const float* b1 = (const float*)d_in[3];
  const float* W1r = (const float*)d_in[4];
  const float* W2l = (const float*)d_in[5];
  const float* b2 = (const float*)d_in[6];
  const float* W2r = (const float*)d_in[7];
  const float* W3l = (const float*)d_in[8];
  const float* b3 = (const float*)d_in[9];
  const float* W3r = (const float*)d_in[10];

  int N = in_sizes[0] / 128;
  int E = in_sizes[1] / 2;
  const int* src = ei;
  const int* dst = ei + E;

  char* wptr = (char*)d_ws;
  auto alloc = [&](size_t bytes) {
    void* p = (void*)wptr;
    wptr += (bytes + 255) & ~(size_t)255;
    return p;
  };
  int* off = (int*)alloc((size_t)(N + 1) * 4);
  int* cursor = (int*)alloc((size_t)N * 4);
  int* col = (int*)alloc((size_t)E * 4);
  int* bsum = (int*)alloc(256 * 4);
  int* boff = (int*)alloc(256 * 4);
  unsigned short* Wth1 = (unsigned short*)alloc(32768 * 2);
  unsigned short* Wth2 = (unsigned short*)alloc(32768 * 2);
  unsigned short* Wth3 = (unsigned short*)alloc(16384 * 2);
  unsigned short* xb = (unsigned short*)alloc((size_t)N * 128 * 2);
  unsigned short* mb = (unsigned short*)alloc((size_t)N * 128 * 2);
  unsigned short* h1 = (unsigned short*)alloc((size_t)N * 128 * 2);
  unsigned short* h2 = (unsigned short*)alloc((size_t)N * 128 * 2);

  float* outLS = (float*)d_out;                     // [N][40]
  float* emb = (float*)d_out + (size_t)N * NCLASS;  // [N][128]

  // CSR build (cursor doubles as histogram)
  hipMemsetAsync(cursor, 0, (size_t)N * 4, stream);
  k_hist<<<2048, 256, 0, stream>>>(dst, E, cursor);
  int nb = (N + 1023) / 1024;
  k_scan1<<<nb, 256, 0, stream>>>(cursor, off, bsum, N);
  k_scan2<<<1, 128, 0, stream>>>(bsum, boff, nb);
  k_scan3<<<(N + 255) / 256, 256, 0, stream>>>(off, boff, cursor, N, E);
  k_fill<<<2048, 256, 0, stream>>>(src, dst, E, cursor, col);

  int n8 = N * 16;
  k_cast<<<(n8 + 255) / 256, 256, 0, stream>>>((const float4*)x, (uint4*)xb, n8);
  k_prepw<<<(81920 + 255) / 256, 256, 0, stream>>>(W1l, W1r, W2l, W2r, W3l, W3r, Wth1,
                                                   Wth2, Wth3);

  int ab = (N * 64 + 255) / 256;
  int gb = (N + 127) / 128;

  // layer 1
  k_aggb<<<ab, 256, 0, stream>>>((const unsigned*)xb, off, col, N, (unsigned*)mb);
  k_gemm_mfma<128, 0><<<gb, 256, 0, stream>>>(mb, xb, Wth1, b1, N, nullptr, h1);
  // layer 2 (emb fp32 + h2 bf16)
  k_aggb<<<ab, 256, 0, stream>>>((const unsigned*)h1, off, col, N, (unsigned*)mb);
  k_gemm_mfma<128, 1><<<gb, 256, 0, stream>>>(mb, h1, Wth2, b2, N, emb, h2);
  // layer 3 + fused log_softmax
  k_aggb<<<ab, 256, 0, stream>>>((const unsigned*)h2, off, col, N, (unsigned*)mb);
  k_gemm_mfma<64, 2><<<gb, 256, 0, stream>>>(mb, h2, Wth3, b3, N, outLS, nullptr);
}

// Round 3
// 444.128 us; speedup vs baseline: 1.9085x; 1.2799x over previous
//
#include <hip/hip_runtime.h>
#include <math.h>

#define NCLASS 40

typedef float f32x4 __attribute__((ext_vector_type(4)));
typedef __bf16 bf16x8 __attribute__((ext_vector_type(8)));

typedef __attribute__((address_space(1))) const void gv_t;
typedef __attribute__((address_space(3))) void lv_t;
#define GLOAD_LDS16(g, l) __builtin_amdgcn_global_load_lds((gv_t*)(g), (lv_t*)(l), 16, 0, 0)

__device__ inline unsigned short f2bf(float f) {
  unsigned u = __float_as_uint(f);
  unsigned r = (u + 0x7fff + ((u >> 16) & 1)) >> 16;
  return (unsigned short)r;
}
__device__ inline float bflo(unsigned v) { return __uint_as_float(v << 16); }
__device__ inline float bfhi(unsigned v) { return __uint_as_float(v & 0xffff0000u); }
__device__ inline float bf2f(unsigned short v) { return __uint_as_float((unsigned)v << 16); }

// ---------------- CSR build (XCD-partitioned by dst range) ----------------
// Blocks with (blockIdx&7)==p own dst range [p*PART,(p+1)*PART): atomics and
// col-line writes stay XCD-local, so L2 absorbs partial-line writes.
__global__ void k_histp(const int* __restrict__ dst, int E, int PART,
                        int* __restrict__ cnt) {
  int p = blockIdx.x & 7;
  int lo = p * PART, hi = lo + PART;
  int i = (blockIdx.x >> 3) * blockDim.x + threadIdx.x;
  int stride = (gridDim.x >> 3) * blockDim.x;
  for (; i < E; i += stride) {
    int d = dst[i];
    if (d >= lo && d < hi) atomicAdd(&cnt[d], 1);
  }
}

__global__ void k_fillp(const int* __restrict__ src, const int* __restrict__ dst, int E,
                        int PART, int* __restrict__ cursor, int* __restrict__ col) {
  int p = blockIdx.x & 7;
  int lo = p * PART, hi = lo + PART;
  int i = (blockIdx.x >> 3) * blockDim.x + threadIdx.x;
  int stride = (gridDim.x >> 3) * blockDim.x;
  for (; i < E; i += stride) {
    int d = dst[i];
    if (d >= lo && d < hi) {
      int pos = atomicAdd(&cursor[d], 1);
      col[pos] = src[i];
    }
  }
}

__global__ void k_scan1(const int* __restrict__ cnt, int* __restrict__ off,
                        int* __restrict__ bsum, int n) {
  __shared__ int tmp[256];
  int tid = threadIdx.x;
  int base = blockIdx.x * 1024 + tid * 4;
  int v0 = 0, v1 = 0, v2 = 0, v3 = 0;
  if (base + 0 < n) v0 = cnt[base + 0];
  if (base + 1 < n) v1 = cnt[base + 1];
  if (base + 2 < n) v2 = cnt[base + 2];
  if (base + 3 < n) v3 = cnt[base + 3];
  int s = v0 + v1 + v2 + v3;
  tmp[tid] = s;
  __syncthreads();
  for (int d = 1; d < 256; d <<= 1) {
    int t = (tid >= d) ? tmp[tid - d] : 0;
    __syncthreads();
    tmp[tid] += t;
    __syncthreads();
  }
  int excl = tmp[tid] - s;
  if (base + 0 < n) off[base + 0] = excl;
  excl += v0;
  if (base + 1 < n) off[base + 1] = excl;
  excl += v1;
  if (base + 2 < n) off[base + 2] = excl;
  excl += v2;
  if (base + 3 < n) off[base + 3] = excl;
  if (tid == 255) bsum[blockIdx.x] = tmp[255];
}

__global__ void k_scan2(const int* __restrict__ bsum, int* __restrict__ boff, int nb) {
  __shared__ int tmp[128];
  int tid = threadIdx.x;
  int v = (tid < nb) ? bsum[tid] : 0;
  tmp[tid] = v;
  __syncthreads();
  for (int d = 1; d < 128; d <<= 1) {
    int t = (tid >= d) ? tmp[tid - d] : 0;
    __syncthreads();
    tmp[tid] += t;
    __syncthreads();
  }
  boff[tid] = tmp[tid] - v;
}

__global__ void k_scan3(int* __restrict__ off, const int* __restrict__ boff,
                        int* __restrict__ cursor, int n, int E) {
  int i = blockIdx.x * blockDim.x + threadIdx.x;
  if (i < n) {
    int o = off[i] + boff[i >> 10];
    off[i] = o;
    cursor[i] = o;
  }
  if (i == 0) off[n] = E;
}

// ---------------- casts / weight prep ----------------
__global__ void k_cast(const float4* __restrict__ x, uint4* __restrict__ xb, int n8) {
  int i = blockIdx.x * blockDim.x + threadIdx.x;
  if (i >= n8) return;
  float4 a = x[i * 2], b = x[i * 2 + 1];
  uint4 o;
  o.x = (unsigned)f2bf(a.x) | ((unsigned)f2bf(a.y) << 16);
  o.y = (unsigned)f2bf(a.z) | ((unsigned)f2bf(a.w) << 16);
  o.z = (unsigned)f2bf(b.x) | ((unsigned)f2bf(b.y) << 16);
  o.w = (unsigned)f2bf(b.z) | ((unsigned)f2bf(b.w) << 16);
  xb[i] = o;
}

// Wth layout: [half][COLS][128] bf16, row-of-128-k contiguous. half0=Wl^T, half1=Wr^T.
__global__ void k_prepw(const float* __restrict__ W1l, const float* __restrict__ W1r,
                        const float* __restrict__ W2l, const float* __restrict__ W2r,
                        const float* __restrict__ W3l, const float* __restrict__ W3r,
                        unsigned short* __restrict__ Wth1, unsigned short* __restrict__ Wth2,
                        unsigned short* __restrict__ Wth3) {
  int idx = blockIdx.x * blockDim.x + threadIdx.x;
  if (idx < 32768) {
    int h = idx >> 14, c = (idx >> 7) & 127, k = idx & 127;
    const float* W = h ? W1r : W1l;
    Wth1[idx] = f2bf(W[k * 128 + c]);
  } else if (idx < 65536) {
    int j = idx - 32768;
    int h = j >> 14, c = (j >> 7) & 127, k = j & 127;
    const float* W = h ? W2r : W2l;
    Wth2[j] = f2bf(W[k * 128 + c]);
  } else if (idx < 65536 + 16384) {
    int j = idx - 65536;
    int h = j >> 13, c = (j >> 7) & 63, k = j & 127;
    float v = 0.f;
    if (c < NCLASS) v = (h ? W3r : W3l)[k * NCLASS + c];
    Wth3[j] = f2bf(v);
  }
}

// ---------------- mean aggregation over bf16 rows (d=128) ----------------
__global__ void k_aggb(const unsigned* __restrict__ X, const int* __restrict__ off,
                       const int* __restrict__ col, int n, unsigned* __restrict__ out) {
  int wid = (blockIdx.x * blockDim.x + threadIdx.x) >> 6;
  int lane = threadIdx.x & 63;
  if (wid >= n) return;
  int s = off[wid], e = off[wid + 1];
  float ax = 0.f, ay = 0.f;
  int j = s;
  for (; j + 4 <= e; j += 4) {
    int s0 = col[j], s1 = col[j + 1], s2 = col[j + 2], s3 = col[j + 3];
    unsigned v0 = X[(size_t)s0 * 64 + lane];
    unsigned v1 = X[(size_t)s1 * 64 + lane];
    unsigned v2 = X[(size_t)s2 * 64 + lane];
    unsigned v3 = X[(size_t)s3 * 64 + lane];
    ax += (bflo(v0) + bflo(v1)) + (bflo(v2) + bflo(v3));
    ay += (bfhi(v0) + bfhi(v1)) + (bfhi(v2) + bfhi(v3));
  }
  for (; j < e; ++j) {
    unsigned v0 = X[(size_t)col[j] * 64 + lane];
    ax += bflo(v0);
    ay += bfhi(v0);
  }
  float inv = 1.0f / fmaxf((float)(e - s), 1.0f);
  out[(size_t)wid * 64 + lane] =
      (unsigned)f2bf(ax * inv) | ((unsigned)f2bf(ay * inv) << 16);
}

// ---------------- MFMA GEMM ----------------
// HALVES=2: A = [Aagg | Aroot], K=256. HALVES=1: A = Aagg only, K=128.
// EPI 0: relu -> outB bf16 [n][128]
// EPI 1: relu -> outB bf16 [n][128] AND outF f32 [n][128]
// EPI 3: cols 0..63 -> outB bf16 [n][64] (Y3, no bias); cols 64..127 -> outF f32
//        [n][64] (R3 = acc + b3 for col-64<40)
template <int COLS, int HALVES, int EPI>
__global__ __launch_bounds__(256) void k_gemm_mfma(
    const unsigned short* __restrict__ Aagg, const unsigned short* __restrict__ Aroot,
    const unsigned short* __restrict__ Wth, const float* __restrict__ bias, int n,
    float* __restrict__ outF, unsigned short* __restrict__ outB) {
  constexpr int RF = 4;
  constexpr int CF = 4;
  __shared__ unsigned short aS[128 * 128];
  __shared__ unsigned short wS[COLS * 128];
  int tid = threadIdx.x;
  int w = tid >> 6, lane = tid & 63, l15 = lane & 15, kg = lane >> 4;
  int rowBase = blockIdx.x * 128;
  int r0 = (w >> 1) * 64;
  int c0 = (w & 1) * 64;

  f32x4 acc[RF][CF];
#pragma unroll
  for (int i = 0; i < RF; ++i)
#pragma unroll
    for (int j = 0; j < CF; ++j) acc[i][j] = (f32x4){0.f, 0.f, 0.f, 0.f};

#pragma unroll
  for (int half = 0; half < HALVES; ++half) {
    if (half) __syncthreads();
    {
      const unsigned short* As = half ? Aroot : Aagg;
#pragma unroll
      for (int it = 0; it < 8; ++it) {
        int row = it * 16 + (tid >> 4);
        int g = rowBase + row;
        g = (g < n) ? g : (n - 1);
        int cb = (tid & 15) << 4;
        int sb = cb ^ ((row & 7) << 4);
        const char* src = (const char*)(As + (size_t)g * 128) + sb;
        char* dst = (char*)aS + it * 4096 + (tid >> 6) * 1024;
        GLOAD_LDS16(src, dst);
      }
      const unsigned short* Ws = Wth + (size_t)half * COLS * 128;
#pragma unroll
      for (int it = 0; it < COLS / 16; ++it) {
        int c = it * 16 + (tid >> 4);
        int cb = (tid & 15) << 4;
        int sb = cb ^ ((c & 7) << 4);
        const char* src = (const char*)(Ws + (size_t)c * 128) + sb;
        char* dst = (char*)wS + it * 4096 + (tid >> 6) * 1024;
        GLOAD_LDS16(src, dst);
      }
      asm volatile("s_waitcnt vmcnt(0)" ::: "memory");
      __syncthreads();
    }
#pragma unroll
    for (int ks = 0; ks < 4; ++ks) {
      int kb = ks * 64 + kg * 16;
      bf16x8 av[RF], bv[CF];
#pragma unroll
      for (int i = 0; i < RF; ++i) {
        int row = r0 + i * 16 + l15;
        av[i] = *(const bf16x8*)((const char*)aS + row * 256 + (kb ^ ((row & 7) << 4)));
      }
#pragma unroll
      for (int j = 0; j < CF; ++j) {
        int c = c0 + j * 16 + l15;
        bv[j] = *(const bf16x8*)((const char*)wS + c * 256 + (kb ^ ((c & 7) << 4)));
      }
#pragma unroll
      for (int i = 0; i < RF; ++i)
#pragma unroll
        for (int j = 0; j < CF; ++j)
          acc[i][j] = __builtin_amdgcn_mfma_f32_16x16x32_bf16(av[i], bv[j], acc[i][j], 0, 0, 0);
    }
  }

  if (EPI == 3) {
    bool leftHalf = (c0 == 0);
    float bcol[CF];
#pragma unroll
    for (int j = 0; j < CF; ++j) {
      int c = c0 + j * 16 + l15;
      bcol[j] = (!leftHalf && (c - 64) < NCLASS) ? bias[c - 64] : 0.f;
    }
#pragma unroll
    for (int i = 0; i < RF; ++i) {
#pragma unroll
      for (int r = 0; r < 4; ++r) {
        int row = rowBase + r0 + i * 16 + kg * 4 + r;
        if (row >= n) continue;
#pragma unroll
        for (int j = 0; j < CF; ++j) {
          int c = c0 + j * 16 + l15;
          if (leftHalf) {
            outB[(size_t)row * 64 + c] = f2bf(acc[i][j][r]);
          } else {
            outF[(size_t)row * 64 + (c - 64)] = acc[i][j][r] + bcol[j];
          }
        }
      }
    }
  } else {
    float bcol[CF];
#pragma unroll
    for (int j = 0; j < CF; ++j) bcol[j] = bias[c0 + j * 16 + l15];
#pragma unroll
    for (int i = 0; i < RF; ++i) {
#pragma unroll
      for (int r = 0; r < 4; ++r) {
        int row = rowBase + r0 + i * 16 + kg * 4 + r;
        if (row >= n) continue;
#pragma unroll
        for (int j = 0; j < CF; ++j) {
          float v = fmaxf(acc[i][j][r] + bcol[j], 0.f);
          int c = c0 + j * 16 + l15;
          outB[(size_t)row * 128 + c] = f2bf(v);
          if (EPI == 1) outF[(size_t)row * 128 + c] = v;
        }
      }
    }
  }
}

// ---------------- layer-3: width-64 mean aggregation + log_softmax ----------------
// Y3 bf16 [n][64] (cols>=40 are zero), R3 f32 [n][64] (= h2@W3r + b3).
__global__ void k_agg3ls(const unsigned short* __restrict__ Y3,
                         const float* __restrict__ R3, const int* __restrict__ off,
                         const int* __restrict__ col, int n, float* __restrict__ out) {
  int wid = (blockIdx.x * blockDim.x + threadIdx.x) >> 6;
  int lane = threadIdx.x & 63;
  if (wid >= n) return;
  int s = off[wid], e = off[wid + 1];
  float acc = 0.f;
  int j = s;
  for (; j + 4 <= e; j += 4) {
    int s0 = col[j], s1 = col[j + 1], s2 = col[j + 2], s3 = col[j + 3];
    float v0 = bf2f(Y3[(size_t)s0 * 64 + lane]);
    float v1 = bf2f(Y3[(size_t)s1 * 64 + lane]);
    float v2 = bf2f(Y3[(size_t)s2 * 64 + lane]);
    float v3 = bf2f(Y3[(size_t)s3 * 64 + lane]);
    acc += (v0 + v1) + (v2 + v3);
  }
  for (; j < e; ++j) acc += bf2f(Y3[(size_t)col[j] * 64 + lane]);
  float inv = 1.0f / fmaxf((float)(e - s), 1.0f);
  float val = -INFINITY;
  if (lane < NCLASS) val = acc * inv + R3[(size_t)wid * 64 + lane];
  float m = val;
  for (int o = 32; o > 0; o >>= 1) m = fmaxf(m, __shfl_xor(m, o));
  float ex = (lane < NCLASS) ? expf(val - m) : 0.f;
  float sum = ex;
  for (int o = 32; o > 0; o >>= 1) sum += __shfl_xor(sum, o);
  float ls = logf(sum);
  if (lane < NCLASS) out[(size_t)wid * NCLASS + lane] = val - m - ls;
}

extern "C" void kernel_launch(void* const* d_in, const int* in_sizes, int n_in,
                              void* d_out, int out_size, void* d_ws, size_t ws_size,
                              hipStream_t stream) {
  const float* x = (const float*)d_in[0];
  const int* ei = (const int*)d_in[1];
  const float* W1l = (const float*)d_in[2];
  const float* b1 = (const float*)d_in[3];
  const float* W1r = (const float*)d_in[4];
  const float* W2l = (const float*)d_in[5];
  const float* b2 = (const float*)d_in[6];
  const float* W2r = (const float*)d_in[7];
  const float* W3l = (const float*)d_in[8];
  const float* b3 = (const float*)d_in[9];
  const float* W3r = (const float*)d_in[10];

  int N = in_sizes[0] / 128;
  int E = in_sizes[1] / 2;
  const int* src = ei;
  const int* dst = ei + E;
  int PART = (N + 7) / 8;

  char* wptr = (char*)d_ws;
  auto alloc = [&](size_t bytes) {
    void* p = (void*)wptr;
    wptr += (bytes + 255) & ~(size_t)255;
    return p;
  };
  int* off = (int*)alloc((size_t)(N + 1) * 4);
  int* cursor = (int*)alloc((size_t)N * 4);
  int* col = (int*)alloc((size_t)E * 4);
  int* bsum = (int*)alloc(256 * 4);
  int* boff = (int*)alloc(256 * 4);
  unsigned short* Wth1 = (unsigned short*)alloc(32768 * 2);
  unsigned short* Wth2 = (unsigned short*)alloc(32768 * 2);
  unsigned short* Wth3 = (unsigned short*)alloc(16384 * 2);
  unsigned short* xb = (unsigned short*)alloc((size_t)N * 128 * 2);
  unsigned short* mb = (unsigned short*)alloc((size_t)N * 128 * 2);
  unsigned short* h1 = (unsigned short*)alloc((size_t)N * 128 * 2);
  unsigned short* h2 = (unsigned short*)alloc((size_t)N * 128 * 2);

  float* outLS = (float*)d_out;                     // [N][40]
  float* emb = (float*)d_out + (size_t)N * NCLASS;  // [N][128]

  // Buffer reuse for layer 3 (mb and h1 are dead after gemm2):
  unsigned short* Y3 = mb;  // bf16 [N][64]
  float* R3 = (float*)h1;   // f32 [N][64]

  // CSR build (cursor doubles as histogram)
  hipMemsetAsync(cursor, 0, (size_t)N * 4, stream);
  k_histp<<<2048, 256, 0, stream>>>(dst, E, PART, cursor);
  int nb = (N + 1023) / 1024;
  k_scan1<<<nb, 256, 0, stream>>>(cursor, off, bsum, N);
  k_scan2<<<1, 128, 0, stream>>>(bsum, boff, nb);
  k_scan3<<<(N + 255) / 256, 256, 0, stream>>>(off, boff, cursor, N, E);
  k_fillp<<<2048, 256, 0, stream>>>(src, dst, E, PART, cursor, col);

  int n8 = N * 16;
  k_cast<<<(n8 + 255) / 256, 256, 0, stream>>>((const float4*)x, (uint4*)xb, n8);
  k_prepw<<<(81920 + 255) / 256, 256, 0, stream>>>(W1l, W1r, W2l, W2r, W3l, W3r, Wth1,
                                                   Wth2, Wth3);

  int ab = (N * 64 + 255) / 256;
  int gb = (N + 127) / 128;

  // layer 1
  k_aggb<<<ab, 256, 0, stream>>>((const unsigned*)xb, off, col, N, (unsigned*)mb);
  k_gemm_mfma<128, 2, 0><<<gb, 256, 0, stream>>>(mb, xb, Wth1, b1, N, nullptr, h1);
  // layer 2 (emb f32 + h2 bf16)
  k_aggb<<<ab, 256, 0, stream>>>((const unsigned*)h1, off, col, N, (unsigned*)mb);
  k_gemm_mfma<128, 2, 1><<<gb, 256, 0, stream>>>(mb, h1, Wth2, b2, N, emb, h2);
  // layer 3: project first (Y3 = h2@W3l bf16, R3 = h2@W3r + b3 f32), then
  // width-64 aggregation with fused log_softmax
  k_gemm_mfma<128, 1, 3><<<gb, 256, 0, stream>>>(h2, nullptr, Wth3, b3, N, R3, Y3);
  k_agg3ls<<<ab, 256, 0, stream>>>(Y3, R3, off, col, N, outLS);
}